// Round 4
// baseline (13.864 us; speedup 1.0000x reference)
//
#include <hip/hip_runtime.h>
#include <hip/hip_bf16.h>
#include <math.h>

#define B_N 8192
#define U_N 256
#define F_N 128
#define UG  64    // u's per block = 4 MFMA n-tiles
#define BT  64    // b-rows per block = 4 waves x 16

typedef __attribute__((ext_vector_type(8))) short short8;   // 8 bf16
typedef __attribute__((ext_vector_type(4))) float f32x4;    // MFMA C/D

static __device__ __forceinline__ unsigned short f2bf(float v) {
  __hip_bfloat16 h = __float2bfloat16(v);   // compiler emits v_cvt_pk_bf16_f32 for pairs
  return *reinterpret_cast<unsigned short*>(&h);
}

// Fused kernel. Block = (64 b-rows) x (64 u's).
// Phase 1: build W fragments (bf16, MFMA-A-ready) in LDS + C[u] partial sums.
// Phase 2: 4 waves x [16 b-rows x 64 u] via 32 MFMAs; W is the A operand so
//          the C/D layout gives each thread u-contiguous float4 stores.
__global__ __launch_bounds__(256, 4) void bp_kernel(
    const float* __restrict__ x, const float* __restrict__ shift,
    const float* __restrict__ semi, const float* __restrict__ sharp,
    const float* __restrict__ mult, float* __restrict__ out) {
  // Wf[tile][kk][lane][j] = W[u0+tile*16+(lane&15)][kk*32+(lane>>4)*8+j]
  // W[u][k] = (k<128) ? 1/sa^2 : 2*s/sa^2
  __shared__ __align__(16) unsigned short Wf[4][8][64][8];  // 32 KB
  __shared__ __align__(16) float Cs[UG];

  const int tid  = threadIdx.x;
  const int lane = tid & 63;
  const int w    = tid >> 6;     // wave 0..3
  const int lg   = lane >> 4;    // 0..3
  const int ln   = lane & 15;    // 0..15
  const int u0   = blockIdx.y * UG;

  // ---- issue x loads early ----
  const int brow0 = blockIdx.x * BT + w * 16;
  const float* xrow = x + (size_t)(brow0 + ln) * F_N;
  float4 xv[8];
#pragma unroll
  for (int s4 = 0; s4 < 4; ++s4) {
    xv[s4 * 2]     = *reinterpret_cast<const float4*>(xrow + s4 * 32 + lg * 8);
    xv[s4 * 2 + 1] = *reinterpret_cast<const float4*>(xrow + s4 * 32 + lg * 8 + 4);
  }

  // ---- phase 1: W fragments + C sums (4 passes of 16 u's) ----
#pragma unroll
  for (int p = 0; p < 4; ++p) {
    const int u_loc = (tid >> 4) + p * 16;   // 0..63
    const int f0    = (tid & 15) * 8;        // 0..120
    const float* sp = shift + (size_t)(u0 + u_loc) * F_N + f0;
    const float* ap = semi  + (size_t)(u0 + u_loc) * F_N + f0;
    float4 s0 = *reinterpret_cast<const float4*>(sp);
    float4 s1 = *reinterpret_cast<const float4*>(sp + 4);
    float4 a0 = *reinterpret_cast<const float4*>(ap);
    float4 a1 = *reinterpret_cast<const float4*>(ap + 4);
    float ss[8] = {s0.x, s0.y, s0.z, s0.w, s1.x, s1.y, s1.z, s1.w};
    float aa[8] = {a0.x, a0.y, a0.z, a0.w, a1.x, a1.y, a1.z, a1.w};
    unsigned short qi[8], qb[8];
    float csum = 0.f;
#pragma unroll
    for (int j = 0; j < 8; ++j) {
      float inv = 1.0f / (aa[j] * aa[j]);
      qi[j] = f2bf(inv);
      qb[j] = f2bf(2.0f * ss[j] * inv);
      csum += ss[j] * ss[j] * inv;
    }
    const int tile = u_loc >> 4;
    const int kkp  = f0 >> 5;                               // 0..3
    const int lnp  = ((f0 >> 3) & 3) * 16 + (u_loc & 15);   // fragment lane
    *reinterpret_cast<uint2*>(&Wf[tile][kkp][lnp][0])     = *reinterpret_cast<uint2*>(qi);
    *reinterpret_cast<uint2*>(&Wf[tile][kkp][lnp][4])     = *reinterpret_cast<uint2*>(qi + 4);
    *reinterpret_cast<uint2*>(&Wf[tile][kkp + 4][lnp][0]) = *reinterpret_cast<uint2*>(qb);
    *reinterpret_cast<uint2*>(&Wf[tile][kkp + 4][lnp][4]) = *reinterpret_cast<uint2*>(qb + 4);
    csum += __shfl_xor(csum, 1, 64);
    csum += __shfl_xor(csum, 2, 64);
    csum += __shfl_xor(csum, 4, 64);
    csum += __shfl_xor(csum, 8, 64);
    if ((lane & 15) == 0) Cs[u_loc] = csum;
  }

  // ---- convert x fragments in-register (B operand: G[b=ln][k=lg*8+j]) ----
  short8 fx2[4], fx1[4];
#pragma unroll
  for (int s4 = 0; s4 < 4; ++s4) {
    float xs[8] = {xv[s4*2].x, xv[s4*2].y, xv[s4*2].z, xv[s4*2].w,
                   xv[s4*2+1].x, xv[s4*2+1].y, xv[s4*2+1].z, xv[s4*2+1].w};
    short8 a2, a1;
#pragma unroll
    for (int j = 0; j < 8; ++j) {
      a2[j] = (short)f2bf(xs[j] * xs[j]);
      a1[j] = (short)f2bf(xs[j]);
    }
    fx2[s4] = a2; fx1[s4] = a1;
  }

  __syncthreads();

  // ---- phase 2: GEMM, K=256 (k<128: x^2*inv ; k>=128: x*2s*inv) ----
  f32x4 acc[4];
#pragma unroll
  for (int t = 0; t < 4; ++t) acc[t] = (f32x4){0.f, 0.f, 0.f, 0.f};
#pragma unroll
  for (int kk = 0; kk < 8; ++kk) {
    short8 a = (kk < 4) ? fx2[kk] : fx1[kk - 4];
#pragma unroll
    for (int t = 0; t < 4; ++t) {
      short8 wv = *reinterpret_cast<const short8*>(&Wf[t][kk][lane][0]);
      // W as A, x as B  ->  D[row=u_local][col=b_local]
      acc[t] = __builtin_amdgcn_mfma_f32_16x16x32_bf16(wv, a, acc[t], 0, 0, 0);
    }
  }

  // ---- epilogue: thread owns b = brow0+ln, u = u0+t*16+lg*4+r (contiguous) ----
  const int brow = brow0 + ln;
#pragma unroll
  for (int t = 0; t < 4; ++t) {
    const int ub = t * 16 + lg * 4;
    const float4 c  = *reinterpret_cast<const float4*>(&Cs[ub]);
    const float4 sh = *reinterpret_cast<const float4*>(&sharp[u0 + ub]);
    const float4 mu = *reinterpret_cast<const float4*>(&mult[u0 + ub]);
    const float cc[4] = {c.x, c.y, c.z, c.w};
    const float shs[4] = {sh.x, sh.y, sh.z, sh.w};
    const float mus[4] = {mu.x, mu.y, mu.z, mu.w};
    float res[4];
#pragma unroll
    for (int r = 0; r < 4; ++r) {
      float quad = acc[t][r] + cc[r];
      float z = shs[r] * (1.0f - quad);
      float e = __expf(-z);                       // inf when saturated
      res[r] = mus[r] * __builtin_amdgcn_rcpf(1.0f + e);  // rcp(inf)=+0 -> ±0
    }
    *reinterpret_cast<float4*>(&out[(size_t)brow * U_N + u0 + ub]) =
        make_float4(res[0], res[1], res[2], res[3]);
  }
}

extern "C" void kernel_launch(void* const* d_in, const int* in_sizes, int n_in,
                              void* d_out, int out_size, void* d_ws, size_t ws_size,
                              hipStream_t stream) {
  (void)in_sizes; (void)n_in; (void)out_size; (void)d_ws; (void)ws_size;
  const float* x     = (const float*)d_in[0];
  const float* shift = (const float*)d_in[1];
  const float* semi  = (const float*)d_in[2];
  const float* sharp = (const float*)d_in[3];
  const float* mult  = (const float*)d_in[4];
  float* out = (float*)d_out;

  bp_kernel<<<dim3(B_N / BT, U_N / UG), 256, 0, stream>>>(x, shift, semi, sharp, mult, out);
}